// Round 4
// baseline (3167.692 us; speedup 1.0000x reference)
//
#include <hip/hip_runtime.h>
#include <cstddef>
#include <cstdint>

#define L_LEN 4096
#define RWID 256
#define SWID 128
#define NLAY 30
#define COOP_GRID 512

typedef __attribute__((ext_vector_type(8))) short bf16x8;
typedef __attribute__((ext_vector_type(4))) float f32x4;

__device__ __forceinline__ ushort f2bf(float x) {
  union { float f; uint32_t u; } v; v.f = x;
  uint32_t r = v.u + 0x7fffu + ((v.u >> 16) & 1u);
  return (ushort)(r >> 16);
}

__device__ __forceinline__ void gload16(const void* g, void* l) {
  __builtin_amdgcn_global_load_lds(
      (const __attribute__((address_space(1))) void*)g,
      (__attribute__((address_space(3))) void*)l, 16, 0, 0);
}

__device__ __forceinline__ f32x4 mfma16(bf16x8 a, bf16x8 b, f32x4 c) {
  return __builtin_amdgcn_mfma_f32_16x16x32_bf16(a, b, c, 0, 0, 0);
}

// monotonic grid barrier: device-scope atomics, fences on both sides (G16)
__device__ __forceinline__ void gridbar(unsigned* cnt, unsigned nb) {
  __syncthreads();
  if (threadIdx.x == 0) {
    __threadfence();   // release: write back my block's stores (cross-XCD)
    unsigned old = __hip_atomic_fetch_add(cnt, 1u, __ATOMIC_ACQ_REL,
                                          __HIP_MEMORY_SCOPE_AGENT);
    unsigned target = (old / nb + 1u) * nb;
    while (__hip_atomic_load(cnt, __ATOMIC_RELAXED, __HIP_MEMORY_SCOPE_AGENT) < target)
      __builtin_amdgcn_s_sleep(2);
    __threadfence();   // acquire: invalidate before reading others' data
  }
  __syncthreads();
}

// ============================ weight prep ============================
// wres[i][fg][co][k], k = tap*256 + cin for k<768; 768..783 = cond; 784..799 = 0
__global__ __launch_bounds__(256) void prep_wres(
    const float* __restrict__ filter_w, const float* __restrict__ gate_w,
    const float* __restrict__ fcond_w, const float* __restrict__ gcond_w,
    ushort* __restrict__ wres)
{
  const int idx = blockIdx.x * 256 + threadIdx.x;   // < 30*2*256*800
  const int k = idx % 800;
  int rest = idx / 800;
  const int co = rest & 255; rest >>= 8;
  const int fg = rest & 1;
  const int i = rest >> 1;
  float v;
  if (k < 768) {
    const int tap = k >> 8, cin = k & 255;
    const float* s = fg ? gate_w : filter_w;
    v = s[(((size_t)i * 256 + co) * 256 + cin) * 3 + tap];
  } else if (k < 784) {
    const float* s = fg ? gcond_w : fcond_w;
    v = s[((size_t)i * 256 + co) * 16 + (k - 768)];
  } else v = 0.f;
  wres[idx] = f2bf(v);
}

// wu[i][m][rc]: m<256 -> feat_w, m>=256 -> skip_w
__global__ __launch_bounds__(256) void prep_wu(
    const float* __restrict__ feat_w, const float* __restrict__ skip_w,
    ushort* __restrict__ wu)
{
  const int idx = blockIdx.x * 256 + threadIdx.x;   // < 30*384*256
  const int rc = idx & 255;
  const int rest = idx >> 8;
  const int m = rest % 384;
  const int i = rest / 384;
  float v = (m < 256) ? feat_w[((size_t)i * 256 + m) * 256 + rc]
                      : skip_w[((size_t)i * 128 + (m - 256)) * 256 + rc];
  wu[idx] = f2bf(v);
}

// condT[4096][32] (cols>=16 zero), wisk[128][256], wfsk[128][128], wfin[256][128], zerobuf
__global__ __launch_bounds__(256) void prep_misc(
    const float* __restrict__ cond, const float* __restrict__ isw,
    const float* __restrict__ fsw, const float* __restrict__ fw,
    ushort* __restrict__ condT, ushort* __restrict__ wisk,
    ushort* __restrict__ wfsk, ushort* __restrict__ wfin,
    ushort* __restrict__ zerobuf)
{
  const int idx = blockIdx.x * 256 + threadIdx.x;
  if (idx < 131072) {
    const int t = idx >> 5, cd = idx & 31;
    condT[idx] = (cd < 16) ? f2bf(cond[(size_t)cd * L_LEN + t]) : (ushort)0;
  } else if (idx < 131072 + 32768) {
    const int j = idx - 131072; wisk[j] = f2bf(isw[j]);
  } else if (idx < 131072 + 32768 + 16384) {
    const int j = idx - (131072 + 32768); wfsk[j] = f2bf(fsw[j]);
  } else if (idx < 131072 + 32768 + 16384 + 32768) {
    const int j = idx - (131072 + 32768 + 16384); wfin[j] = f2bf(fw[j]);
  } else if (idx < 131072 + 32768 + 16384 + 32768 + 512) {
    zerobuf[idx - (131072 + 32768 + 16384 + 32768)] = 0;
  }
}

// ============================ init feature ============================
__global__ __launch_bounds__(256) void init_feat(
    const float* __restrict__ x, const float* __restrict__ w,
    const float* __restrict__ b, float* __restrict__ featT_f32,
    ushort* __restrict__ featT_bf16)
{
  const int t = blockIdx.x, c = threadIdx.x;
  const float xm = (t > 0) ? x[t - 1] : 0.f;
  const float x0 = x[t];
  const float xp = (t < L_LEN - 1) ? x[t + 1] : 0.f;
  const float v = b[c] + w[c * 3] * xm + w[c * 3 + 1] * x0 + w[c * 3 + 2] * xp;
  featT_f32[(size_t)t * 256 + c] = v;
  featT_bf16[(size_t)t * 256 + c] = f2bf(v);
}

// ============================ persistent 30-layer cooperative kernel ============================
// grid 512 x 256. Residual: (tb = bid&63)*64 t, (cb = bid>>6)*32 co.
// Update: same t-tile, m0 = (bid>>6)*48 (384 = 8*48; frags 16-aligned).
__global__ __launch_bounds__(256, 2) void layers_coop(
    const ushort* __restrict__ condT,
    const ushort* __restrict__ wres_all,
    const ushort* __restrict__ wu_all,
    const ushort* __restrict__ zerobuf,
    ushort* __restrict__ featT_bf16,
    float*  __restrict__ featT_f32,
    ushort* __restrict__ resT,
    float*  __restrict__ skipT_f32,
    unsigned* __restrict__ bar)
{
  __shared__ ushort lds[2][4096];
  const int bid = blockIdx.x;
  const int tid = threadIdx.x;
  const int lane = tid & 63;
  const int w    = tid >> 6;

  const int srow = lane >> 2;
  const int soct = (lane & 3) ^ ((srow >> 1) & 3);
  const int rl   = lane & 15;
  const int octr = (lane >> 4) ^ ((rl >> 1) & 3);

  const int t0 = (bid & 63) * 64;
  const int cb = bid >> 6;
  const int co0 = cb * 32;
  const int m0  = cb * 48;

  const unsigned nb = gridDim.x;

  for (int layer = 0; layer < NLAY; ++layer) {
    const int d = 1 << (layer % 10);
    const ushort* wres = wres_all + (size_t)layer * (2 * 256 * 800);
    const ushort* wu   = wu_all   + (size_t)layer * (384 * 256);

    // ---------------- residual phase ----------------
    {
      const int fgA  = w >> 1;
      const int arow = ((w & 1) << 4) + srow;
      const ushort* asrc0 = wres + ((size_t)fgA * 256 + (co0 + arow)) * 800 + soct * 8;
      const int aLds = fgA * 1024 + (w & 1) * 512;
      const int bLds = 2048 + w * 512;
      const int aoff = rl * 32 + octr * 8;
      const int boff = 2048 + (w * 16 + rl) * 32 + octr * 8;

      f32x4 accf[2] = {}; f32x4 accg[2] = {};

      auto stage = [&](int kc, int buf) {
        const int k0 = kc * 32;
        gload16(asrc0 + k0, &lds[buf][aLds]);
        const int rB = w * 16 + srow;
        const ushort* bsrc;
        if (kc < 24) {
          const int tap = kc >> 3, cin0 = (kc & 7) * 32;
          const int tt = t0 + rB + (tap - 1) * d;
          bsrc = (tt >= 0 && tt < L_LEN)
                   ? featT_bf16 + (size_t)tt * 256 + cin0 + soct * 8
                   : zerobuf;
        } else {
          bsrc = condT + (size_t)(t0 + rB) * 32 + soct * 8;
        }
        gload16(bsrc, &lds[buf][bLds]);
      };

      stage(0, 0);
      __syncthreads();
      for (int kc = 0; kc < 25; ++kc) {
        const int cur = kc & 1;
        if (kc + 1 < 25) stage(kc + 1, cur ^ 1);
        const ushort* base = lds[cur];
        bf16x8 af0 = *(const bf16x8*)(base + aoff);
        bf16x8 af1 = *(const bf16x8*)(base + aoff + 512);
        bf16x8 ag0 = *(const bf16x8*)(base + aoff + 1024);
        bf16x8 ag1 = *(const bf16x8*)(base + aoff + 1536);
        bf16x8 b0  = *(const bf16x8*)(base + boff);
        accf[0] = mfma16(af0, b0, accf[0]);
        accf[1] = mfma16(af1, b0, accf[1]);
        accg[0] = mfma16(ag0, b0, accg[0]);
        accg[1] = mfma16(ag1, b0, accg[1]);
        __syncthreads();
      }

      const int cobase = co0 + (lane >> 4) * 4;
      const int t = t0 + w * 16 + rl;
#pragma unroll
      for (int m = 0; m < 2; ++m) {
        const f32x4 f = accf[m], g = accg[m];
        ushort4 ov;
        float o[4];
#pragma unroll
        for (int r = 0; r < 4; ++r) {
          const float ff = f[r], gg = g[r];
          const float sig = 1.f / (1.f + __expf(-ff));
          const float ag2 = fabsf(gg);
          float th = 1.f - 2.f / (__expf(2.f * ag2) + 1.f);
          th = (gg < 0.f) ? -th : th;
          o[r] = sig * th;
        }
        ov.x = f2bf(o[0]); ov.y = f2bf(o[1]); ov.z = f2bf(o[2]); ov.w = f2bf(o[3]);
        *(ushort4*)&resT[(size_t)t * 256 + cobase + m * 16] = ov;
      }
    }
    gridbar(bar, nb);

    // ---------------- update phase (48m x 64t) ----------------
    {
      const int awave = (w < 3) ? w : 0;  // wave 3 stages no A
      const ushort* asrc0 = wu + (size_t)(m0 + awave * 16 + srow) * 256 + soct * 8;
      const int aLds = awave * 512;
      const int bLds = 1536 + w * 512;
      const int aoff = rl * 32 + octr * 8;
      const int boff = 1536 + (w * 16 + rl) * 32 + octr * 8;

      f32x4 acc[3] = {};

      auto stageU = [&](int kc, int buf) {
        const int k0 = kc * 32;
        if (w < 3) gload16(asrc0 + k0, &lds[buf][aLds]);
        const int rB = w * 16 + srow;
        gload16(resT + (size_t)(t0 + rB) * 256 + k0 + soct * 8, &lds[buf][bLds]);
      };

      stageU(0, 0);
      __syncthreads();
      for (int kc = 0; kc < 8; ++kc) {
        const int cur = kc & 1;
        if (kc + 1 < 8) stageU(kc + 1, cur ^ 1);
        const ushort* base = lds[cur];
        bf16x8 b0 = *(const bf16x8*)(base + boff);
        acc[0] = mfma16(*(const bf16x8*)(base + aoff), b0, acc[0]);
        acc[1] = mfma16(*(const bf16x8*)(base + aoff + 512), b0, acc[1]);
        acc[2] = mfma16(*(const bf16x8*)(base + aoff + 1024), b0, acc[2]);
        __syncthreads();
      }

      const int t = t0 + w * 16 + rl;
#pragma unroll
      for (int j = 0; j < 3; ++j) {
        const int mm = m0 + j * 16 + (lane >> 4) * 4;
        const f32x4 a = acc[j];
        if (mm < 256) {
          float4* p = (float4*)&featT_f32[(size_t)t * 256 + mm];
          float4 v = *p;
          v.x += a[0]; v.y += a[1]; v.z += a[2]; v.w += a[3];
          *p = v;
          ushort4 ov; ov.x = f2bf(v.x); ov.y = f2bf(v.y); ov.z = f2bf(v.z); ov.w = f2bf(v.w);
          *(ushort4*)&featT_bf16[(size_t)t * 256 + mm] = ov;
        } else {
          float4* p = (float4*)&skipT_f32[(size_t)t * 128 + (mm - 256)];
          float4 v = *p;
          v.x += a[0]; v.y += a[1]; v.z += a[2]; v.w += a[3];
          *p = v;
        }
      }
    }
    gridbar(bar, nb);
  }
}

// ============================ generic 1x1 MFMA GEMM ============================
// MODE 0: acc+bias -> fp32 [t][128] overwrite (init skip)
// MODE 1: relu(acc+bias) -> bf16 [t][128] (skip2)
// MODE 2: acc+bias -> fp32 [m][4096] (final out)
template<int MODE, int KLEN>
__global__ __launch_bounds__(256) void gemm_mfma(
    const ushort* __restrict__ A,    // [M][KLEN] bf16
    const ushort* __restrict__ B,    // [4096][KLEN] bf16
    const float* __restrict__ bias,  // [M]
    void* __restrict__ outp)
{
  __shared__ ushort lds[2][3072];
  const int t0 = blockIdx.x * 64;
  const int m0 = blockIdx.y * 32;
  const int tid = threadIdx.x;
  const int lane = tid & 63;
  const int w    = tid >> 6;

  const int srow = lane >> 2;
  const int soct = (lane & 3) ^ ((srow >> 1) & 3);

  const ushort* asrc0 = A + (size_t)(m0 + (w & 1) * 16 + srow) * KLEN + soct * 8;
  const int aLds = (w & 1) * 512;
  const int bLds = 1024 + w * 512;

  const int rl   = lane & 15;
  const int octr = (lane >> 4) ^ ((rl >> 1) & 3);
  const int aoff = rl * 32 + octr * 8;
  const int boff = 1024 + (w * 16 + rl) * 32 + octr * 8;

  f32x4 acc[2] = {};
  constexpr int KSTEPS = KLEN / 32;

  auto stage = [&](int kc, int buf) {
    const int k0 = kc * 32;
    if (w < 2) gload16(asrc0 + k0, &lds[buf][aLds]);
    const int rB = w * 16 + srow;
    gload16(B + (size_t)(t0 + rB) * KLEN + k0 + soct * 8, &lds[buf][bLds]);
  };

  stage(0, 0);
  __syncthreads();
  for (int kc = 0; kc < KSTEPS; ++kc) {
    const int cur = kc & 1;
    if (kc + 1 < KSTEPS) stage(kc + 1, cur ^ 1);
    const ushort* base = lds[cur];
    bf16x8 a0 = *(const bf16x8*)(base + aoff);
    bf16x8 a1 = *(const bf16x8*)(base + aoff + 512);
    bf16x8 b0 = *(const bf16x8*)(base + boff);
    acc[0] = mfma16(a0, b0, acc[0]);
    acc[1] = mfma16(a1, b0, acc[1]);
    __syncthreads();
  }

  const int mbase = m0 + (lane >> 4) * 4;
  const int t = t0 + w * 16 + rl;
#pragma unroll
  for (int m = 0; m < 2; ++m) {
    const int mm = mbase + m * 16;
    const float4 bb = *(const float4*)&bias[mm];
    const f32x4 a = acc[m];
    float o[4] = {a[0] + bb.x, a[1] + bb.y, a[2] + bb.z, a[3] + bb.w};
    if (MODE == 0) {
      *(float4*)&((float*)outp)[(size_t)t * 128 + mm] = make_float4(o[0], o[1], o[2], o[3]);
    } else if (MODE == 1) {
      ushort4 ov;
      ov.x = f2bf(fmaxf(o[0], 0.f)); ov.y = f2bf(fmaxf(o[1], 0.f));
      ov.z = f2bf(fmaxf(o[2], 0.f)); ov.w = f2bf(fmaxf(o[3], 0.f));
      *(ushort4*)&((ushort*)outp)[(size_t)t * 128 + mm] = ov;
    } else {
      float* op = (float*)outp;
#pragma unroll
      for (int r = 0; r < 4; ++r) op[(size_t)(mm + r) * L_LEN + t] = o[r];
    }
  }
}

// relu + fp32->bf16 (float4 vectorized)
__global__ __launch_bounds__(256) void relu_cvt(
    const float* __restrict__ in, ushort* __restrict__ outv, int n4)
{
  const int i = blockIdx.x * 256 + threadIdx.x;
  if (i >= n4) return;
  const float4 v = ((const float4*)in)[i];
  ushort4 o;
  o.x = f2bf(fmaxf(v.x, 0.f)); o.y = f2bf(fmaxf(v.y, 0.f));
  o.z = f2bf(fmaxf(v.z, 0.f)); o.w = f2bf(fmaxf(v.w, 0.f));
  ((ushort4*)outv)[i] = o;
}

// ============================ launch ============================
extern "C" void kernel_launch(void* const* d_in, const int* in_sizes, int n_in,
                              void* d_out, int out_size, void* d_ws, size_t ws_size,
                              hipStream_t stream) {
  const float* x            = (const float*)d_in[0];
  const float* cond         = (const float*)d_in[1];
  const float* init_w       = (const float*)d_in[2];
  const float* init_b       = (const float*)d_in[3];
  const float* init_skip_w  = (const float*)d_in[4];
  const float* init_skip_b  = (const float*)d_in[5];
  const float* filter_w     = (const float*)d_in[6];
  const float* gate_w       = (const float*)d_in[7];
  const float* skip_w       = (const float*)d_in[8];
  const float* feat_w       = (const float*)d_in[9];
  const float* fcond_w      = (const float*)d_in[10];
  const float* gcond_w      = (const float*)d_in[11];
  const float* final_skip_w = (const float*)d_in[12];
  const float* final_skip_b = (const float*)d_in[13];
  const float* final_w      = (const float*)d_in[14];
  const float* final_b      = (const float*)d_in[15];
  float* out = (float*)d_out;
  (void)in_sizes; (void)n_in; (void)out_size; (void)ws_size;

  char* ws = (char*)d_ws;
  size_t off = 0;
  auto alloc = [&](size_t bytes) { void* p = ws + off; off = (off + bytes + 255) & ~(size_t)255; return p; };
  float*  featT_f32  = (float*) alloc((size_t)L_LEN * 256 * 4);
  ushort* featT_bf16 = (ushort*)alloc((size_t)L_LEN * 256 * 2);
  ushort* resT       = (ushort*)alloc((size_t)L_LEN * 256 * 2);
  float*  skipT_f32  = (float*) alloc((size_t)L_LEN * 128 * 4);
  ushort* skipR      = (ushort*)alloc((size_t)L_LEN * 128 * 2);
  ushort* skip2R     = (ushort*)alloc((size_t)L_LEN * 128 * 2);
  ushort* condT      = (ushort*)alloc((size_t)L_LEN * 32 * 2);
  ushort* wres       = (ushort*)alloc((size_t)NLAY * 2 * 256 * 800 * 2);
  ushort* wu         = (ushort*)alloc((size_t)NLAY * 384 * 256 * 2);
  ushort* wisk       = (ushort*)alloc((size_t)128 * 256 * 2);
  ushort* wfsk       = (ushort*)alloc((size_t)128 * 128 * 2);
  ushort* wfin       = (ushort*)alloc((size_t)256 * 128 * 2);
  ushort* zerobuf    = (ushort*)alloc(1024);
  unsigned* bar      = (unsigned*)alloc(256);

  const dim3 B256(256);
  prep_wres<<<48000, B256, 0, stream>>>(filter_w, gate_w, fcond_w, gcond_w, wres);
  prep_wu<<<11520, B256, 0, stream>>>(feat_w, skip_w, wu);
  prep_misc<<<833, B256, 0, stream>>>(cond, init_skip_w, final_skip_w, final_w,
                                      condT, wisk, wfsk, wfin, zerobuf);
  init_feat<<<L_LEN, B256, 0, stream>>>(x, init_w, init_b, featT_f32, featT_bf16);
  gemm_mfma<0, 256><<<dim3(64, 4), B256, 0, stream>>>(wisk, featT_bf16, init_skip_b, skipT_f32);

  // zero the grid-barrier counter (ws is poisoned each call), then run the
  // persistent cooperative layer loop.
  hipMemsetAsync(bar, 0, sizeof(unsigned) * 2, stream);
  {
    const ushort* a_condT = condT; const ushort* a_wres = wres;
    const ushort* a_wu = wu; const ushort* a_zero = zerobuf;
    ushort* a_fb = featT_bf16; float* a_ff = featT_f32;
    ushort* a_res = resT; float* a_skip = skipT_f32; unsigned* a_bar = bar;
    void* cargs[] = { (void*)&a_condT, (void*)&a_wres, (void*)&a_wu, (void*)&a_zero,
                      (void*)&a_fb, (void*)&a_ff, (void*)&a_res, (void*)&a_skip,
                      (void*)&a_bar };
    hipLaunchCooperativeKernel((const void*)layers_coop, dim3(COOP_GRID), B256,
                               cargs, 0, stream);
  }

  relu_cvt<<<512, B256, 0, stream>>>(skipT_f32, skipR, (L_LEN * 128) / 4);
  gemm_mfma<1, 128><<<dim3(64, 4), B256, 0, stream>>>(wfsk, skipR, final_skip_b, skip2R);
  gemm_mfma<2, 128><<<dim3(64, 8), B256, 0, stream>>>(wfin, skip2R, final_b, out);
}

// Round 5
// 634.970 us; speedup vs baseline: 4.9887x; 4.9887x over previous
//
#include <hip/hip_runtime.h>
#include <cstddef>
#include <cstdint>

#define L_LEN 4096
#define RWID 256
#define SWID 128
#define NLAY 30

typedef __attribute__((ext_vector_type(8))) short bf16x8;
typedef __attribute__((ext_vector_type(4))) float f32x4;

__device__ __forceinline__ ushort f2bf(float x) {
  union { float f; uint32_t u; } v; v.f = x;
  uint32_t r = v.u + 0x7fffu + ((v.u >> 16) & 1u);
  return (ushort)(r >> 16);
}

__device__ __forceinline__ void gload16(const void* g, void* l) {
  __builtin_amdgcn_global_load_lds(
      (const __attribute__((address_space(1))) void*)g,
      (__attribute__((address_space(3))) void*)l, 16, 0, 0);
}

__device__ __forceinline__ f32x4 mfma16(bf16x8 a, bf16x8 b, f32x4 c) {
  return __builtin_amdgcn_mfma_f32_16x16x32_bf16(a, b, c, 0, 0, 0);
}

// counted vmcnt wait (T4): keep newer prefetch stages in flight across barriers
template<int N> __device__ __forceinline__ void waitvm() {
  asm volatile("s_waitcnt vmcnt(%0)" :: "i"(N) : "memory");
}
// raw barrier (no implicit vmcnt(0) drain, unlike __syncthreads)
__device__ __forceinline__ void blockbar() {
  __builtin_amdgcn_sched_barrier(0);
  asm volatile("s_barrier" ::: "memory");
  __builtin_amdgcn_sched_barrier(0);
}

// ============================ weight prep ============================
// wres[i][fg][co][k], k = tap*256 + cin for k<768; 768..783 = cond; 784..799 = 0
__global__ __launch_bounds__(256) void prep_wres(
    const float* __restrict__ filter_w, const float* __restrict__ gate_w,
    const float* __restrict__ fcond_w, const float* __restrict__ gcond_w,
    ushort* __restrict__ wres)
{
  const int idx = blockIdx.x * 256 + threadIdx.x;   // < 30*2*256*800
  const int k = idx % 800;
  int rest = idx / 800;
  const int co = rest & 255; rest >>= 8;
  const int fg = rest & 1;
  const int i = rest >> 1;
  float v;
  if (k < 768) {
    const int tap = k >> 8, cin = k & 255;
    const float* s = fg ? gate_w : filter_w;
    v = s[(((size_t)i * 256 + co) * 256 + cin) * 3 + tap];
  } else if (k < 784) {
    const float* s = fg ? gcond_w : fcond_w;
    v = s[((size_t)i * 256 + co) * 16 + (k - 768)];
  } else v = 0.f;
  wres[idx] = f2bf(v);
}

// wu[i][m][rc]: m<256 -> feat_w, m>=256 -> skip_w
__global__ __launch_bounds__(256) void prep_wu(
    const float* __restrict__ feat_w, const float* __restrict__ skip_w,
    ushort* __restrict__ wu)
{
  const int idx = blockIdx.x * 256 + threadIdx.x;   // < 30*384*256
  const int rc = idx & 255;
  const int rest = idx >> 8;
  const int m = rest % 384;
  const int i = rest / 384;
  float v = (m < 256) ? feat_w[((size_t)i * 256 + m) * 256 + rc]
                      : skip_w[((size_t)i * 128 + (m - 256)) * 256 + rc];
  wu[idx] = f2bf(v);
}

// condT[4096][32] (cols>=16 zero), wisk[128][256], wfsk[128][128], wfin[256][128], zerobuf
__global__ __launch_bounds__(256) void prep_misc(
    const float* __restrict__ cond, const float* __restrict__ isw,
    const float* __restrict__ fsw, const float* __restrict__ fw,
    ushort* __restrict__ condT, ushort* __restrict__ wisk,
    ushort* __restrict__ wfsk, ushort* __restrict__ wfin,
    ushort* __restrict__ zerobuf)
{
  const int idx = blockIdx.x * 256 + threadIdx.x;
  if (idx < 131072) {
    const int t = idx >> 5, cd = idx & 31;
    condT[idx] = (cd < 16) ? f2bf(cond[(size_t)cd * L_LEN + t]) : (ushort)0;
  } else if (idx < 131072 + 32768) {
    const int j = idx - 131072; wisk[j] = f2bf(isw[j]);
  } else if (idx < 131072 + 32768 + 16384) {
    const int j = idx - (131072 + 32768); wfsk[j] = f2bf(fsw[j]);
  } else if (idx < 131072 + 32768 + 16384 + 32768) {
    const int j = idx - (131072 + 32768 + 16384); wfin[j] = f2bf(fw[j]);
  } else if (idx < 131072 + 32768 + 16384 + 32768 + 512) {
    zerobuf[idx - (131072 + 32768 + 16384 + 32768)] = 0;
  }
}

// ============================ init feature ============================
__global__ __launch_bounds__(256) void init_feat(
    const float* __restrict__ x, const float* __restrict__ w,
    const float* __restrict__ b, float* __restrict__ featT_f32,
    ushort* __restrict__ featT_bf16)
{
  const int t = blockIdx.x, c = threadIdx.x;
  const float xm = (t > 0) ? x[t - 1] : 0.f;
  const float x0 = x[t];
  const float xp = (t < L_LEN - 1) ? x[t + 1] : 0.f;
  const float v = b[c] + w[c * 3] * xm + w[c * 3 + 1] * x0 + w[c * 3 + 2] * xp;
  featT_f32[(size_t)t * 256 + c] = v;
  featT_bf16[(size_t)t * 256 + c] = f2bf(v);
}

// ============================ residual (f/g) MFMA ============================
// Tile 32co x 64t, grid (64,8)=512 (2/CU). 25 K-chunks of 32.
// Depth-3 staging ring; all 4 waves issue 2 gload16/stage (uniform).
__global__ __launch_bounds__(256) void residual_mfma(
    const ushort* __restrict__ featT,   // [4096][256] bf16
    const ushort* __restrict__ condT,   // [4096][32] bf16
    const ushort* __restrict__ wres,    // [2][256][800] bf16 (this layer)
    const ushort* __restrict__ zerobuf,
    ushort* __restrict__ resT,          // [4096][256] bf16
    int d)
{
  __shared__ ushort lds[3][4096];
  const int t0  = blockIdx.x * 64;
  const int co0 = blockIdx.y * 32;
  const int tid = threadIdx.x;
  const int lane = tid & 63;
  const int w    = tid >> 6;

  const int srow = lane >> 2;
  const int soct = (lane & 3) ^ ((srow >> 1) & 3);

  const int fgA  = w >> 1;                  // waves 0,1 -> filter A; 2,3 -> gate A
  const int arow = ((w & 1) << 4) + srow;
  const ushort* asrc0 = wres + ((size_t)fgA * 256 + (co0 + arow)) * 800 + soct * 8;
  const int aLds = fgA * 1024 + (w & 1) * 512;
  const int bLds = 2048 + w * 512;

  const int rl   = lane & 15;
  const int octr = (lane >> 4) ^ ((rl >> 1) & 3);
  const int aoff = rl * 32 + octr * 8;
  const int boff = 2048 + (w * 16 + rl) * 32 + octr * 8;

  f32x4 accf[2] = {}; f32x4 accg[2] = {};

  auto stage = [&](int kc, int buf) {
    const int k0 = kc * 32;
    gload16(asrc0 + k0, &lds[buf][aLds]);
    const int rB = w * 16 + srow;
    const ushort* bsrc;
    if (kc < 24) {
      const int tap = kc >> 3, cin0 = (kc & 7) * 32;
      const int tt = t0 + rB + (tap - 1) * d;
      bsrc = (tt >= 0 && tt < L_LEN)
               ? featT + (size_t)tt * 256 + cin0 + soct * 8
               : zerobuf;
    } else {
      bsrc = condT + (size_t)(t0 + rB) * 32 + soct * 8;
    }
    gload16(bsrc, &lds[buf][bLds]);
  };

  stage(0, 0);
  stage(1, 1);
  for (int kc = 0; kc < 25; ++kc) {
    if (kc + 2 < 25) { stage(kc + 2, (kc + 2) % 3); waitvm<4>(); }
    else if (kc + 1 < 25) waitvm<2>();
    else waitvm<0>();
    blockbar();
    const ushort* base = lds[kc % 3];
    bf16x8 af0 = *(const bf16x8*)(base + aoff);
    bf16x8 af1 = *(const bf16x8*)(base + aoff + 512);
    bf16x8 ag0 = *(const bf16x8*)(base + aoff + 1024);
    bf16x8 ag1 = *(const bf16x8*)(base + aoff + 1536);
    bf16x8 b0  = *(const bf16x8*)(base + boff);
    accf[0] = mfma16(af0, b0, accf[0]);
    accf[1] = mfma16(af1, b0, accf[1]);
    accg[0] = mfma16(ag0, b0, accg[0]);
    accg[1] = mfma16(ag1, b0, accg[1]);
    blockbar();
  }

  const int cobase = co0 + (lane >> 4) * 4;
  const int t = t0 + w * 16 + rl;
#pragma unroll
  for (int m = 0; m < 2; ++m) {
    const f32x4 f = accf[m], g = accg[m];
    ushort4 ov;
    float o[4];
#pragma unroll
    for (int r = 0; r < 4; ++r) {
      const float ff = f[r], gg = g[r];
      const float sig = 1.f / (1.f + __expf(-ff));
      const float ag2 = fabsf(gg);
      float th = 1.f - 2.f / (__expf(2.f * ag2) + 1.f);
      th = (gg < 0.f) ? -th : th;
      o[r] = sig * th;
    }
    ov.x = f2bf(o[0]); ov.y = f2bf(o[1]); ov.z = f2bf(o[2]); ov.w = f2bf(o[3]);
    *(ushort4*)&resT[(size_t)t * 256 + cobase + m * 16] = ov;
  }
}

// ============================ update MFMA ============================
// Tile 32m x 64t, grid (64,12)=768 (3/CU). K=256 (8 chunks). Depth-3 ring.
// Waves 0,1 stage A+B (2 loads/stage); waves 2,3 stage B only (1 load/stage).
__global__ __launch_bounds__(256) void update_mfma(
    const ushort* __restrict__ resT,   // [4096][256]
    const ushort* __restrict__ wu,     // [384][256] this layer
    float* __restrict__ featT_f32, ushort* __restrict__ featT_bf16,
    float* __restrict__ skipT_f32)
{
  __shared__ ushort lds[3][3072];
  const int t0 = blockIdx.x * 64;
  const int m0 = blockIdx.y * 32;
  const int tid = threadIdx.x;
  const int lane = tid & 63;
  const int w    = tid >> 6;

  const int srow = lane >> 2;
  const int soct = (lane & 3) ^ ((srow >> 1) & 3);

  const ushort* asrc0 = wu + (size_t)(m0 + (w & 1) * 16 + srow) * 256 + soct * 8;
  const int aLds = (w & 1) * 512;
  const int bLds = 1024 + w * 512;

  const int rl   = lane & 15;
  const int octr = (lane >> 4) ^ ((rl >> 1) & 3);
  const int aoff = rl * 32 + octr * 8;
  const int boff = 1024 + (w * 16 + rl) * 32 + octr * 8;

  f32x4 acc[2] = {};
  const bool twoLoads = (w < 2);

  auto stage = [&](int kc, int buf) {
    const int k0 = kc * 32;
    if (w < 2) gload16(asrc0 + k0, &lds[buf][aLds]);
    const int rB = w * 16 + srow;
    gload16(resT + (size_t)(t0 + rB) * 256 + k0 + soct * 8, &lds[buf][bLds]);
  };

  stage(0, 0);
  stage(1, 1);
  for (int kc = 0; kc < 8; ++kc) {
    if (kc + 2 < 8) {
      stage(kc + 2, (kc + 2) % 3);
      if (twoLoads) waitvm<4>(); else waitvm<2>();
    } else if (kc + 1 < 8) {
      if (twoLoads) waitvm<2>(); else waitvm<1>();
    } else waitvm<0>();
    blockbar();
    const ushort* base = lds[kc % 3];
    bf16x8 a0 = *(const bf16x8*)(base + aoff);
    bf16x8 a1 = *(const bf16x8*)(base + aoff + 512);
    bf16x8 b0 = *(const bf16x8*)(base + boff);
    acc[0] = mfma16(a0, b0, acc[0]);
    acc[1] = mfma16(a1, b0, acc[1]);
    blockbar();
  }

  const int mbase = m0 + (lane >> 4) * 4;
  const int t = t0 + w * 16 + rl;
#pragma unroll
  for (int m = 0; m < 2; ++m) {
    const int mm = mbase + m * 16;
    const f32x4 a = acc[m];
    if (m0 < 256) {
      float4* p = (float4*)&featT_f32[(size_t)t * 256 + mm];
      float4 v = *p;
      v.x += a[0]; v.y += a[1]; v.z += a[2]; v.w += a[3];
      *p = v;
      ushort4 ov; ov.x = f2bf(v.x); ov.y = f2bf(v.y); ov.z = f2bf(v.z); ov.w = f2bf(v.w);
      *(ushort4*)&featT_bf16[(size_t)t * 256 + mm] = ov;
    } else {
      float4* p = (float4*)&skipT_f32[(size_t)t * 128 + (mm - 256)];
      float4 v = *p;
      v.x += a[0]; v.y += a[1]; v.z += a[2]; v.w += a[3];
      *p = v;
    }
  }
}

// ============================ generic 1x1 MFMA GEMM ============================
// MODE 0: acc+bias -> fp32 [t][128] overwrite (init skip)
// MODE 1: relu(acc+bias) -> bf16 [t][128] (skip2)
// MODE 2: acc+bias -> fp32 [m][4096] (final out)
template<int MODE, int KLEN>
__global__ __launch_bounds__(256) void gemm_mfma(
    const ushort* __restrict__ A,    // [M][KLEN] bf16
    const ushort* __restrict__ B,    // [4096][KLEN] bf16
    const float* __restrict__ bias,  // [M]
    void* __restrict__ outp)
{
  __shared__ ushort lds[3][3072];
  const int t0 = blockIdx.x * 64;
  const int m0 = blockIdx.y * 32;
  const int tid = threadIdx.x;
  const int lane = tid & 63;
  const int w    = tid >> 6;

  const int srow = lane >> 2;
  const int soct = (lane & 3) ^ ((srow >> 1) & 3);

  const ushort* asrc0 = A + (size_t)(m0 + (w & 1) * 16 + srow) * KLEN + soct * 8;
  const int aLds = (w & 1) * 512;
  const int bLds = 1024 + w * 512;

  const int rl   = lane & 15;
  const int octr = (lane >> 4) ^ ((rl >> 1) & 3);
  const int aoff = rl * 32 + octr * 8;
  const int boff = 1024 + (w * 16 + rl) * 32 + octr * 8;

  f32x4 acc[2] = {};
  constexpr int NC = KLEN / 32;
  const bool twoLoads = (w < 2);

  auto stage = [&](int kc, int buf) {
    const int k0 = kc * 32;
    if (w < 2) gload16(asrc0 + k0, &lds[buf][aLds]);
    const int rB = w * 16 + srow;
    gload16(B + (size_t)(t0 + rB) * KLEN + k0 + soct * 8, &lds[buf][bLds]);
  };

  stage(0, 0);
  stage(1, 1);
  for (int kc = 0; kc < NC; ++kc) {
    if (kc + 2 < NC) {
      stage(kc + 2, (kc + 2) % 3);
      if (twoLoads) waitvm<4>(); else waitvm<2>();
    } else if (kc + 1 < NC) {
      if (twoLoads) waitvm<2>(); else waitvm<1>();
    } else waitvm<0>();
    blockbar();
    const ushort* base = lds[kc % 3];
    bf16x8 a0 = *(const bf16x8*)(base + aoff);
    bf16x8 a1 = *(const bf16x8*)(base + aoff + 512);
    bf16x8 b0 = *(const bf16x8*)(base + boff);
    acc[0] = mfma16(a0, b0, acc[0]);
    acc[1] = mfma16(a1, b0, acc[1]);
    blockbar();
  }

  const int mbase = m0 + (lane >> 4) * 4;
  const int t = t0 + w * 16 + rl;
#pragma unroll
  for (int m = 0; m < 2; ++m) {
    const int mm = mbase + m * 16;
    const float4 bb = *(const float4*)&bias[mm];
    const f32x4 a = acc[m];
    float o[4] = {a[0] + bb.x, a[1] + bb.y, a[2] + bb.z, a[3] + bb.w};
    if (MODE == 0) {
      *(float4*)&((float*)outp)[(size_t)t * 128 + mm] = make_float4(o[0], o[1], o[2], o[3]);
    } else if (MODE == 1) {
      ushort4 ov;
      ov.x = f2bf(fmaxf(o[0], 0.f)); ov.y = f2bf(fmaxf(o[1], 0.f));
      ov.z = f2bf(fmaxf(o[2], 0.f)); ov.w = f2bf(fmaxf(o[3], 0.f));
      *(ushort4*)&((ushort*)outp)[(size_t)t * 128 + mm] = ov;
    } else {
      float* op = (float*)outp;
#pragma unroll
      for (int r = 0; r < 4; ++r) op[(size_t)(mm + r) * L_LEN + t] = o[r];
    }
  }
}

// relu + fp32->bf16 (float4 vectorized)
__global__ __launch_bounds__(256) void relu_cvt(
    const float* __restrict__ in, ushort* __restrict__ outv, int n4)
{
  const int i = blockIdx.x * 256 + threadIdx.x;
  if (i >= n4) return;
  const float4 v = ((const float4*)in)[i];
  ushort4 o;
  o.x = f2bf(fmaxf(v.x, 0.f)); o.y = f2bf(fmaxf(v.y, 0.f));
  o.z = f2bf(fmaxf(v.z, 0.f)); o.w = f2bf(fmaxf(v.w, 0.f));
  ((ushort4*)outv)[i] = o;
}

// ============================ launch ============================
extern "C" void kernel_launch(void* const* d_in, const int* in_sizes, int n_in,
                              void* d_out, int out_size, void* d_ws, size_t ws_size,
                              hipStream_t stream) {
  const float* x            = (const float*)d_in[0];
  const float* cond         = (const float*)d_in[1];
  const float* init_w       = (const float*)d_in[2];
  const float* init_b       = (const float*)d_in[3];
  const float* init_skip_w  = (const float*)d_in[4];
  const float* init_skip_b  = (const float*)d_in[5];
  const float* filter_w     = (const float*)d_in[6];
  const float* gate_w       = (const float*)d_in[7];
  const float* skip_w       = (const float*)d_in[8];
  const float* feat_w       = (const float*)d_in[9];
  const float* fcond_w      = (const float*)d_in[10];
  const float* gcond_w      = (const float*)d_in[11];
  const float* final_skip_w = (const float*)d_in[12];
  const float* final_skip_b = (const float*)d_in[13];
  const float* final_w      = (const float*)d_in[14];
  const float* final_b      = (const float*)d_in[15];
  float* out = (float*)d_out;
  (void)in_sizes; (void)n_in; (void)out_size; (void)ws_size;

  char* ws = (char*)d_ws;
  size_t off = 0;
  auto alloc = [&](size_t bytes) { void* p = ws + off; off = (off + bytes + 255) & ~(size_t)255; return p; };
  float*  featT_f32  = (float*) alloc((size_t)L_LEN * 256 * 4);
  ushort* featT_bf16 = (ushort*)alloc((size_t)L_LEN * 256 * 2);
  ushort* resT       = (ushort*)alloc((size_t)L_LEN * 256 * 2);
  float*  skipT_f32  = (float*) alloc((size_t)L_LEN * 128 * 4);
  ushort* skipR      = (ushort*)alloc((size_t)L_LEN * 128 * 2);
  ushort* skip2R     = (ushort*)alloc((size_t)L_LEN * 128 * 2);
  ushort* condT      = (ushort*)alloc((size_t)L_LEN * 32 * 2);
  ushort* wres       = (ushort*)alloc((size_t)NLAY * 2 * 256 * 800 * 2);
  ushort* wu         = (ushort*)alloc((size_t)NLAY * 384 * 256 * 2);
  ushort* wisk       = (ushort*)alloc((size_t)128 * 256 * 2);
  ushort* wfsk       = (ushort*)alloc((size_t)128 * 128 * 2);
  ushort* wfin       = (ushort*)alloc((size_t)256 * 128 * 2);
  ushort* zerobuf    = (ushort*)alloc(1024);

  const dim3 B256(256);
  prep_wres<<<48000, B256, 0, stream>>>(filter_w, gate_w, fcond_w, gcond_w, wres);
  prep_wu<<<11520, B256, 0, stream>>>(feat_w, skip_w, wu);
  prep_misc<<<833, B256, 0, stream>>>(cond, init_skip_w, final_skip_w, final_w,
                                      condT, wisk, wfsk, wfin, zerobuf);
  init_feat<<<L_LEN, B256, 0, stream>>>(x, init_w, init_b, featT_f32, featT_bf16);
  gemm_mfma<0, 256><<<dim3(64, 4), B256, 0, stream>>>(wisk, featT_bf16, init_skip_b, skipT_f32);

  for (int i = 0; i < NLAY; ++i) {
    const int d = 1 << (i % 10);
    residual_mfma<<<dim3(64, 8), B256, 0, stream>>>(
        featT_bf16, condT, wres + (size_t)i * 2 * 256 * 800, zerobuf, resT, d);
    update_mfma<<<dim3(64, 12), B256, 0, stream>>>(
        resT, wu + (size_t)i * 384 * 256, featT_f32, featT_bf16, skipT_f32);
  }

  relu_cvt<<<512, B256, 0, stream>>>(skipT_f32, skipR, (L_LEN * 128) / 4);
  gemm_mfma<1, 128><<<dim3(64, 4), B256, 0, stream>>>(wfsk, skipR, final_skip_b, skip2R);
  gemm_mfma<2, 128><<<dim3(64, 8), B256, 0, stream>>>(wfin, skip2R, final_b, out);
}